// Round 1
// baseline (99.665 us; speedup 1.0000x reference)
//
#include <hip/hip_runtime.h>
#include <hip/hip_bf16.h>

// SAGAN self-attention, B=4 N=4096 C=64 d=8.
// Kernel 1: projections -> ws as bf16: Qb[b][n][8] (pre-scaled by log2e),
//           Kb[b][n][8], Vt[b][c][n] (pre-transposed = PV B-frag layout).
// Kernel 2: flash attention, 1 wave per 16 q-rows, MFMA 16x16x32 bf16,
//           swapped QK^T (S^T = K*Q) so softmax is row-per-ql, 8-shfl
//           redistribution into the PV A-fragment. No LDS, no barriers.

typedef __attribute__((ext_vector_type(4))) float f32x4;
typedef __attribute__((ext_vector_type(8))) short short8;

#define LOG2E 1.44269504088896340736f

#if __has_builtin(__builtin_amdgcn_exp2f)
#define EXP2(x) __builtin_amdgcn_exp2f(x)
#else
#define EXP2(x) exp2f(x)
#endif

__device__ __forceinline__ unsigned short f2bf(float f) {
    __hip_bfloat16 h = __float2bfloat16(f);
    union { __hip_bfloat16 h; unsigned short u; } cv;
    cv.h = h;
    return cv.u;
}

__device__ __forceinline__ unsigned int pk2bf(float lo, float hi) {
    return (unsigned int)f2bf(lo) | ((unsigned int)f2bf(hi) << 16);
}

// ---------------------------------------------------------------------------
// Projection kernel: 256 blocks x 256 threads, 64 tokens per block.
// ---------------------------------------------------------------------------
__global__ __launch_bounds__(256) void sagan_proj_kernel(
    const float* __restrict__ x,
    const float* __restrict__ Wq, const float* __restrict__ bq,
    const float* __restrict__ Wk, const float* __restrict__ bk,
    const float* __restrict__ Wv, const float* __restrict__ bv,
    unsigned short* __restrict__ Qb, unsigned short* __restrict__ Kb,
    unsigned short* __restrict__ Vt)
{
    __shared__ float xs[64][68];   // +4 pad: conflict-free strided reads
    const int tid = threadIdx.x;
    const int blk = blockIdx.x;          // 0..255
    const int tglob0 = blk << 6;         // first global token of this block
    const int b  = tglob0 >> 12;         // batch (N=4096 per batch)
    const int nb = tglob0 & 4095;        // n base within batch

    // stage x tile [64 tokens][64 ch]
    {
        const int t = tid >> 2, q4 = tid & 3;
        const float* src = x + (size_t)(tglob0 + t) * 64 + q4 * 16;
        #pragma unroll
        for (int e = 0; e < 4; ++e)
            *(f32x4*)&xs[t][q4 * 16 + e * 4] = *(const f32x4*)(src + e * 4);
    }
    __syncthreads();

    // ---- V projection: thread = (channel c = tid&63, wave tg = tid>>6) ----
    // writes Vt[b][c][n] transposed, 16 consecutive n per thread (2x uint4)
    {
        const int c  = tid & 63;
        const int tg = tid >> 6;
        float wcol[64];
        #pragma unroll
        for (int cc = 0; cc < 64; ++cc) wcol[cc] = Wv[cc * 64 + c];
        const float bvc = bv[c];
        unsigned int wv[8];
        #pragma unroll
        for (int j = 0; j < 16; ++j) {
            const int tok = tg * 16 + j;      // wave-uniform -> LDS broadcast
            float acc = bvc;
            #pragma unroll
            for (int c4 = 0; c4 < 16; ++c4) {
                f32x4 xv = *(const f32x4*)&xs[tok][c4 * 4];
                acc += xv[0] * wcol[c4 * 4 + 0] + xv[1] * wcol[c4 * 4 + 1]
                     + xv[2] * wcol[c4 * 4 + 2] + xv[3] * wcol[c4 * 4 + 3];
            }
            if (j & 1) wv[j >> 1] |= ((unsigned int)f2bf(acc)) << 16;
            else       wv[j >> 1]  =  (unsigned int)f2bf(acc);
        }
        unsigned short* dst = Vt + ((size_t)(b * 64 + c) * 4096) + nb + tg * 16;
        *(uint4*)dst       = make_uint4(wv[0], wv[1], wv[2], wv[3]);
        *((uint4*)dst + 1) = make_uint4(wv[4], wv[5], wv[6], wv[7]);
    }

    // ---- Q/K projections: thread = (token = tid>>2, d-pair = (tid&3)*2) ----
    {
        const int tok = tid >> 2;
        const int dd  = (tid & 3) * 2;
        float q0 = bq[dd], q1 = bq[dd + 1];
        float k0 = bk[dd], k1 = bk[dd + 1];
        #pragma unroll
        for (int cc = 0; cc < 64; ++cc) {
            const float  xv = xs[tok][cc];
            const float2 wq = *(const float2*)&Wq[cc * 8 + dd];
            const float2 wk = *(const float2*)&Wk[cc * 8 + dd];
            q0 += xv * wq.x; q1 += xv * wq.y;
            k0 += xv * wk.x; k1 += xv * wk.y;
        }
        const size_t toff = (size_t)(tglob0 + tok) * 8 + dd;
        // fold log2(e) into Q so softmax uses exp2 directly
        *(unsigned int*)(Qb + toff) = pk2bf(q0 * LOG2E, q1 * LOG2E);
        *(unsigned int*)(Kb + toff) = pk2bf(k0, k1);
    }
}

// ---------------------------------------------------------------------------
// Flash attention kernel: grid = B * N/16 = 1024 blocks, 1 wave each.
// Wave owns 16 q-rows; loops k in chunks of 32.
// S^T = mfma(K_frag, Q_frag): out col = lane&15 = q, row = (lane>>4)*4+reg = k.
// PV: O = mfma(P_frag, Vt_frag): out row = q, col = c.
// ---------------------------------------------------------------------------
__global__ __launch_bounds__(64) void sagan_flash_kernel(
    const unsigned short* __restrict__ Qb, const unsigned short* __restrict__ Kb,
    const unsigned short* __restrict__ Vt, const float* __restrict__ x,
    const float* __restrict__ gamma_p, float* __restrict__ out)
{
    const int lane = threadIdx.x;
    const int g  = lane >> 4;
    const int ql = lane & 15;
    const int blk = blockIdx.x;
    const int b = blk >> 8;                  // 256 q-tiles per batch
    const int qbase = (blk & 255) << 4;

    const short8 zfrag = {0, 0, 0, 0, 0, 0, 0, 0};

    // Q as B-operand of S^T: lane holds Q[qbase+ql][d = g*8+i]; d>=8 is zero pad
    short8 qf;
    {
        short8 qv = *(const short8*)(Qb + (size_t)(b * 4096 + qbase + ql) * 8);
        qf = (g == 0) ? qv : zfrag;
    }

    const unsigned short* Kbase = Kb + (size_t)b * 4096 * 8;
    const unsigned short* Vbase = Vt + (size_t)b * 64 * 4096;

    f32x4 acc0 = {0.f, 0.f, 0.f, 0.f}, acc1 = acc0, acc2 = acc0, acc3 = acc0;
    float m = -1e30f, lsum = 0.f;

    for (int kt = 0; kt < 4096; kt += 32) {
        // K as A-operand: lane holds K[kt + t*16 + ql][d = g*8+i], zero for d>=8
        short8 k0 = *(const short8*)(Kbase + (size_t)(kt + ql) * 8);
        short8 k1 = *(const short8*)(Kbase + (size_t)(kt + 16 + ql) * 8);
        const short8 ka0 = (g == 0) ? k0 : zfrag;
        const short8 ka1 = (g == 0) ? k1 : zfrag;

        // V as B-operand: lane holds V[kt + g*8+i][ct*16 + ql] = Vt[c][k] rows
        const short8 vf0 = *(const short8*)(Vbase + (size_t)(ql)      * 4096 + kt + g * 8);
        const short8 vf1 = *(const short8*)(Vbase + (size_t)(16 + ql) * 4096 + kt + g * 8);
        const short8 vf2 = *(const short8*)(Vbase + (size_t)(32 + ql) * 4096 + kt + g * 8);
        const short8 vf3 = *(const short8*)(Vbase + (size_t)(48 + ql) * 4096 + kt + g * 8);

        const f32x4 zc = {0.f, 0.f, 0.f, 0.f};
        f32x4 s0 = __builtin_amdgcn_mfma_f32_16x16x32_bf16(ka0, qf, zc, 0, 0, 0);
        f32x4 s1 = __builtin_amdgcn_mfma_f32_16x16x32_bf16(ka1, qf, zc, 0, 0, 0);
        // lane now holds S[q=ql][k = kt + t*16 + g*4 + reg] (log2 domain)

        // ---- online softmax (row q = ql spread over 4 lane-groups) ----
        float cm = fmaxf(fmaxf(fmaxf(s0[0], s0[1]), fmaxf(s0[2], s0[3])),
                         fmaxf(fmaxf(s1[0], s1[1]), fmaxf(s1[2], s1[3])));
        cm = fmaxf(cm, __shfl_xor(cm, 16));
        cm = fmaxf(cm, __shfl_xor(cm, 32));
        const float mnew = fmaxf(m, cm);
        const float corr = EXP2(m - mnew);   // first iter: exp2(-1e30) = 0

        float p[8];
        #pragma unroll
        for (int r = 0; r < 4; ++r) {
            p[r]     = EXP2(s0[r] - mnew);
            p[4 + r] = EXP2(s1[r] - mnew);
        }
        float cs = ((p[0] + p[1]) + (p[2] + p[3])) + ((p[4] + p[5]) + (p[6] + p[7]));
        cs += __shfl_xor(cs, 16);
        cs += __shfl_xor(cs, 32);
        lsum = lsum * corr + cs;
        m = mnew;

        // rescale accumulators; acc row index is q = g*4+r, corr lives at ql=q
        float corr4[4];
        #pragma unroll
        for (int r = 0; r < 4; ++r) corr4[r] = __shfl(corr, (g << 2) | r);
        #pragma unroll
        for (int r = 0; r < 4; ++r) {
            acc0[r] *= corr4[r]; acc1[r] *= corr4[r];
            acc2[r] *= corr4[r]; acc3[r] *= corr4[r];
        }

        // ---- pack P to bf16 pairs & redistribute into PV A-fragment ----
        // source lane (g,ql) holds k-local = t*16 + g*4 + reg for tiles t=0,1
        const unsigned int W00 = pk2bf(p[0], p[1]);   // t0, k-local g*4+{0,1}
        const unsigned int W01 = pk2bf(p[2], p[3]);   // t0, k-local g*4+{2,3}
        const unsigned int W10 = pk2bf(p[4], p[5]);   // t1, k-local g*4+{0,1}
        const unsigned int W11 = pk2bf(p[6], p[7]);   // t1, k-local g*4+{2,3}

        // dest lane (g,ql) needs P[ql][k = g*8 + i], i=0..7:
        // tile = g>>1, srcgroup = 2*(g&1) + (pair>>1), word = pair&1
        const int sLo = ql + ((g & 1) << 5);
        const int sHi = sLo + 16;
        union { unsigned int w[4]; short8 v; } pu;
        {
            unsigned int a0 = __shfl(W00, sLo), b0 = __shfl(W10, sLo);
            unsigned int a1 = __shfl(W01, sLo), b1 = __shfl(W11, sLo);
            unsigned int a2 = __shfl(W00, sHi), b2 = __shfl(W10, sHi);
            unsigned int a3 = __shfl(W01, sHi), b3 = __shfl(W11, sHi);
            const bool lo = (g < 2);
            pu.w[0] = lo ? a0 : b0;
            pu.w[1] = lo ? a1 : b1;
            pu.w[2] = lo ? a2 : b2;
            pu.w[3] = lo ? a3 : b3;
        }

        acc0 = __builtin_amdgcn_mfma_f32_16x16x32_bf16(pu.v, vf0, acc0, 0, 0, 0);
        acc1 = __builtin_amdgcn_mfma_f32_16x16x32_bf16(pu.v, vf1, acc1, 0, 0, 0);
        acc2 = __builtin_amdgcn_mfma_f32_16x16x32_bf16(pu.v, vf2, acc2, 0, 0, 0);
        acc3 = __builtin_amdgcn_mfma_f32_16x16x32_bf16(pu.v, vf3, acc3, 0, 0, 0);
    }

    // ---- epilogue: O = acc / lsum; out = gamma*O + x ----
    const float linv = 1.0f / lsum;          // lsum >= 1 always
    float linv4[4];
    #pragma unroll
    for (int r = 0; r < 4; ++r) linv4[r] = __shfl(linv, (g << 2) | r);

    const float gm = gamma_p[0];
    #pragma unroll
    for (int r = 0; r < 4; ++r) {
        const int row = qbase + (g << 2) + r;
        const size_t rowoff = ((size_t)(b * 4096 + row)) * 64;
        out[rowoff + ql]      = gm * (acc0[r] * linv4[r]) + x[rowoff + ql];
        out[rowoff + 16 + ql] = gm * (acc1[r] * linv4[r]) + x[rowoff + 16 + ql];
        out[rowoff + 32 + ql] = gm * (acc2[r] * linv4[r]) + x[rowoff + 32 + ql];
        out[rowoff + 48 + ql] = gm * (acc3[r] * linv4[r]) + x[rowoff + 48 + ql];
    }
}

// ---------------------------------------------------------------------------
extern "C" void kernel_launch(void* const* d_in, const int* in_sizes, int n_in,
                              void* d_out, int out_size, void* d_ws, size_t ws_size,
                              hipStream_t stream) {
    const float* x  = (const float*)d_in[0];
    const float* Wq = (const float*)d_in[1];
    const float* bq = (const float*)d_in[2];
    const float* Wk = (const float*)d_in[3];
    const float* bk = (const float*)d_in[4];
    const float* Wv = (const float*)d_in[5];
    const float* bv = (const float*)d_in[6];
    const float* gm = (const float*)d_in[7];
    float* out = (float*)d_out;

    // ws layout (bf16): Qb[4][4096][8] | Kb[4][4096][8] | Vt[4][64][4096]
    unsigned short* Qb = (unsigned short*)d_ws;
    unsigned short* Kb = Qb + 131072;
    unsigned short* Vt = Kb + 131072;   // total 2.62 MB

    hipLaunchKernelGGL(sagan_proj_kernel, dim3(256), dim3(256), 0, stream,
                       x, Wq, bq, Wk, bk, Wv, bv, Qb, Kb, Vt);
    hipLaunchKernelGGL(sagan_flash_kernel, dim3(1024), dim3(64), 0, stream,
                       Qb, Kb, Vt, x, gm, out);
}

// Round 2
// 81.612 us; speedup vs baseline: 1.2212x; 1.2212x over previous
//
#include <hip/hip_runtime.h>
#include <hip/hip_bf16.h>

// SAGAN self-attention, B=4 N=4096 C=64 d=8.
// Kernel 1: projections -> ws as bf16: Qb[b][n][8] (pre-scaled by log2e),
//           Kb[b][n][8], Vt[b][c][n] (pre-transposed = PV B-frag layout).
// Kernel 2: flash attention, 1024 blocks x 8 waves; wave w owns k-range
//           [w*512, w*512+512) for the block's 16 q-rows (intra-block
//           k-split for occupancy), online softmax with defer-max (T13),
//           LDS merge of the 8 partials at the end.

typedef __attribute__((ext_vector_type(4))) float f32x4;
typedef __attribute__((ext_vector_type(8))) short short8;

#define LOG2E 1.44269504088896340736f

#if __has_builtin(__builtin_amdgcn_exp2f)
#define EXP2(x) __builtin_amdgcn_exp2f(x)
#else
#define EXP2(x) exp2f(x)
#endif

__device__ __forceinline__ unsigned short f2bf(float f) {
    __hip_bfloat16 h = __float2bfloat16(f);
    union { __hip_bfloat16 h; unsigned short u; } cv;
    cv.h = h;
    return cv.u;
}

__device__ __forceinline__ unsigned int pk2bf(float lo, float hi) {
    return (unsigned int)f2bf(lo) | ((unsigned int)f2bf(hi) << 16);
}

// ---------------------------------------------------------------------------
// Projection kernel: 256 blocks x 512 threads, 64 tokens per block.
// ---------------------------------------------------------------------------
__global__ __launch_bounds__(512) void sagan_proj_kernel(
    const float* __restrict__ x,
    const float* __restrict__ Wq, const float* __restrict__ bq,
    const float* __restrict__ Wk, const float* __restrict__ bk,
    const float* __restrict__ Wv, const float* __restrict__ bv,
    unsigned short* __restrict__ Qb, unsigned short* __restrict__ Kb,
    unsigned short* __restrict__ Vt)
{
    __shared__ float xs[64][68];   // +4 pad: conflict-free strided reads
    const int tid = threadIdx.x;
    const int blk = blockIdx.x;          // 0..255
    const int tglob0 = blk << 6;         // first global token of this block
    const int b  = tglob0 >> 12;         // batch (N=4096 per batch)
    const int nb = tglob0 & 4095;        // n base within batch

    // stage x tile [64 tokens][64 ch]: 8 floats per thread
    {
        const int t = tid >> 3, q8 = tid & 7;
        const float* src = x + (size_t)(tglob0 + t) * 64 + q8 * 8;
        *(f32x4*)&xs[t][q8 * 8]     = *(const f32x4*)(src);
        *(f32x4*)&xs[t][q8 * 8 + 4] = *(const f32x4*)(src + 4);
    }
    __syncthreads();

    // ---- V projection: thread = (channel c = tid&63, group tg = tid>>6) ----
    // writes Vt[b][c][n] transposed, 8 consecutive n per thread (1x uint4)
    {
        const int c  = tid & 63;
        const int tg = tid >> 6;             // 0..7
        float wcol[64];
        #pragma unroll
        for (int cc = 0; cc < 64; ++cc) wcol[cc] = Wv[cc * 64 + c];
        const float bvc = bv[c];
        unsigned int wv[4];
        #pragma unroll
        for (int j = 0; j < 8; ++j) {
            const int tok = tg * 8 + j;       // wave-uniform -> LDS broadcast
            float acc = bvc;
            #pragma unroll
            for (int c4 = 0; c4 < 16; ++c4) {
                f32x4 xv = *(const f32x4*)&xs[tok][c4 * 4];
                acc += xv[0] * wcol[c4 * 4 + 0] + xv[1] * wcol[c4 * 4 + 1]
                     + xv[2] * wcol[c4 * 4 + 2] + xv[3] * wcol[c4 * 4 + 3];
            }
            if (j & 1) wv[j >> 1] |= ((unsigned int)f2bf(acc)) << 16;
            else       wv[j >> 1]  =  (unsigned int)f2bf(acc);
        }
        unsigned short* dst = Vt + ((size_t)(b * 64 + c) * 4096) + nb + tg * 8;
        *(uint4*)dst = make_uint4(wv[0], wv[1], wv[2], wv[3]);
    }

    // ---- Q/K projections: thread = (token = tid>>3, d = tid&7) ----
    {
        const int tok = tid >> 3;
        const int dd  = tid & 7;
        float q0 = bq[dd];
        float k0 = bk[dd];
        #pragma unroll
        for (int cc = 0; cc < 64; ++cc) {
            const float xv = xs[tok][cc];
            q0 += xv * Wq[cc * 8 + dd];
            k0 += xv * Wk[cc * 8 + dd];
        }
        const size_t toff = (size_t)(tglob0 + tok) * 8 + dd;
        // fold log2(e) into Q so softmax uses exp2 directly
        Qb[toff] = f2bf(q0 * LOG2E);
        Kb[toff] = f2bf(k0);
    }
}

// ---------------------------------------------------------------------------
// Flash attention kernel: grid = B * N/16 = 1024 blocks, 512 threads (8 waves).
// Wave w owns k in [w*512, w*512+512) for the block's 16 q-rows.
// S^T = mfma(K_frag, Q_frag): out col = lane&15 = q, row = (lane>>4)*4+reg = k.
// PV: O = mfma(P_frag, Vt_frag): out row = q, col = c.
// Defer-max: skip rescale while per-chunk max <= m + 8 (exp2 domain).
// ---------------------------------------------------------------------------
__global__ __launch_bounds__(512, 8) void sagan_flash_kernel(
    const unsigned short* __restrict__ Qb, const unsigned short* __restrict__ Kb,
    const unsigned short* __restrict__ Vt, const float* __restrict__ x,
    const float* __restrict__ gamma_p, float* __restrict__ out)
{
    __shared__ float sacc[8][16][68];   // [wave][q-row][col] (+4 pad)
    __shared__ float sml[8][2][16];     // [wave][m/l][q-row]

    const int tid  = threadIdx.x;
    const int lane = tid & 63;
    const int w    = tid >> 6;               // wave id = k-split index
    const int g    = lane >> 4;
    const int ql   = lane & 15;
    const int blk  = blockIdx.x;
    const int b    = blk >> 8;               // 256 q-tiles per batch
    const int qbase = (blk & 255) << 4;

    const short8 zfrag = {0, 0, 0, 0, 0, 0, 0, 0};

    // Q as B-operand of S^T: lane holds Q[qbase+ql][d = g*8+i]; d>=8 zero pad
    short8 qf;
    {
        short8 qv = *(const short8*)(Qb + (size_t)(b * 4096 + qbase + ql) * 8);
        qf = (g == 0) ? qv : zfrag;
    }

    const unsigned short* Kbase = Kb + (size_t)b * 4096 * 8;
    const unsigned short* Vbase = Vt + (size_t)b * 64 * 4096;

    f32x4 acc0 = {0.f, 0.f, 0.f, 0.f}, acc1 = acc0, acc2 = acc0, acc3 = acc0;
    float m = -1e30f, lsum = 0.f;

    const int kt0 = w << 9;                  // 512 k per wave
    for (int kt = kt0; kt < kt0 + 512; kt += 32) {
        // K as A-operand: lane holds K[kt + t*16 + ql][d = g*8+i], 0 for d>=8
        short8 k0 = *(const short8*)(Kbase + (size_t)(kt + ql) * 8);
        short8 k1 = *(const short8*)(Kbase + (size_t)(kt + 16 + ql) * 8);
        const short8 ka0 = (g == 0) ? k0 : zfrag;
        const short8 ka1 = (g == 0) ? k1 : zfrag;

        // V as B-operand: lane holds V[kt + g*8+i][ct*16 + ql] = Vt rows
        const short8 vf0 = *(const short8*)(Vbase + (size_t)(ql)      * 4096 + kt + g * 8);
        const short8 vf1 = *(const short8*)(Vbase + (size_t)(16 + ql) * 4096 + kt + g * 8);
        const short8 vf2 = *(const short8*)(Vbase + (size_t)(32 + ql) * 4096 + kt + g * 8);
        const short8 vf3 = *(const short8*)(Vbase + (size_t)(48 + ql) * 4096 + kt + g * 8);

        const f32x4 zc = {0.f, 0.f, 0.f, 0.f};
        f32x4 s0 = __builtin_amdgcn_mfma_f32_16x16x32_bf16(ka0, qf, zc, 0, 0, 0);
        f32x4 s1 = __builtin_amdgcn_mfma_f32_16x16x32_bf16(ka1, qf, zc, 0, 0, 0);
        // lane holds S[q=ql][k = kt + t*16 + g*4 + reg] (log2 domain)

        // ---- online softmax with defer-max (T13, tau=8) ----
        float cm = fmaxf(fmaxf(fmaxf(s0[0], s0[1]), fmaxf(s0[2], s0[3])),
                         fmaxf(fmaxf(s1[0], s1[1]), fmaxf(s1[2], s1[3])));
        if (!__all(cm - m <= 8.f)) {
            // rare path: max grew beyond headroom -> full rescale
            cm = fmaxf(cm, __shfl_xor(cm, 16));
            cm = fmaxf(cm, __shfl_xor(cm, 32));      // row max, all 4 groups
            const float mnew = fmaxf(m, cm);
            const float corr = EXP2(m - mnew);       // first iter: 0
            float corr4[4];
            #pragma unroll
            for (int r = 0; r < 4; ++r) corr4[r] = __shfl(corr, (g << 2) | r);
            #pragma unroll
            for (int r = 0; r < 4; ++r) {
                acc0[r] *= corr4[r]; acc1[r] *= corr4[r];
                acc2[r] *= corr4[r]; acc3[r] *= corr4[r];
            }
            lsum *= corr;
            m = mnew;
        }

        float p[8];
        #pragma unroll
        for (int r = 0; r < 4; ++r) {
            p[r]     = EXP2(s0[r] - m);
            p[4 + r] = EXP2(s1[r] - m);
        }
        float cs = ((p[0] + p[1]) + (p[2] + p[3])) + ((p[4] + p[5]) + (p[6] + p[7]));
        cs += __shfl_xor(cs, 16);
        cs += __shfl_xor(cs, 32);
        lsum += cs;

        // ---- pack P to bf16 pairs & redistribute into PV A-fragment ----
        // source lane (g,ql) holds k-local = t*16 + g*4 + reg for tiles t=0,1
        const unsigned int W00 = pk2bf(p[0], p[1]);
        const unsigned int W01 = pk2bf(p[2], p[3]);
        const unsigned int W10 = pk2bf(p[4], p[5]);
        const unsigned int W11 = pk2bf(p[6], p[7]);

        // dest lane (g,ql) needs P[ql][k = g*8 + i], i=0..7
        const int sLo = ql + ((g & 1) << 5);
        const int sHi = sLo + 16;
        union { unsigned int w[4]; short8 v; } pu;
        {
            unsigned int a0 = __shfl(W00, sLo), b0 = __shfl(W10, sLo);
            unsigned int a1 = __shfl(W01, sLo), b1 = __shfl(W11, sLo);
            unsigned int a2 = __shfl(W00, sHi), b2 = __shfl(W10, sHi);
            unsigned int a3 = __shfl(W01, sHi), b3 = __shfl(W11, sHi);
            const bool lo = (g < 2);
            pu.w[0] = lo ? a0 : b0;
            pu.w[1] = lo ? a1 : b1;
            pu.w[2] = lo ? a2 : b2;
            pu.w[3] = lo ? a3 : b3;
        }

        acc0 = __builtin_amdgcn_mfma_f32_16x16x32_bf16(pu.v, vf0, acc0, 0, 0, 0);
        acc1 = __builtin_amdgcn_mfma_f32_16x16x32_bf16(pu.v, vf1, acc1, 0, 0, 0);
        acc2 = __builtin_amdgcn_mfma_f32_16x16x32_bf16(pu.v, vf2, acc2, 0, 0, 0);
        acc3 = __builtin_amdgcn_mfma_f32_16x16x32_bf16(pu.v, vf3, acc3, 0, 0, 0);
    }

    // ---- write partials to LDS ----
    #pragma unroll
    for (int r = 0; r < 4; ++r) {
        const int row = (g << 2) | r;
        sacc[w][row][ql]      = acc0[r];
        sacc[w][row][16 + ql] = acc1[r];
        sacc[w][row][32 + ql] = acc2[r];
        sacc[w][row][48 + ql] = acc3[r];
    }
    if (g == 0) { sml[w][0][ql] = m; sml[w][1][ql] = lsum; }
    __syncthreads();

    // ---- merge 8 partials: thread -> (row = tid>>5, cols col, col+32) ----
    {
        const int row = tid >> 5;
        const int col = tid & 31;
        float M = sml[0][0][row];
        #pragma unroll
        for (int ww = 1; ww < 8; ++ww) M = fmaxf(M, sml[ww][0][row]);
        float L = 0.f, O0 = 0.f, O1 = 0.f;
        #pragma unroll
        for (int ww = 0; ww < 8; ++ww) {
            const float sc = EXP2(sml[ww][0][row] - M);
            L  += sml[ww][1][row] * sc;
            O0 += sacc[ww][row][col]      * sc;
            O1 += sacc[ww][row][col + 32] * sc;
        }
        const float Li = 1.0f / L;
        const float gm = gamma_p[0];
        const size_t rowoff = ((size_t)(b * 4096 + qbase + row)) * 64;
        out[rowoff + col]      = gm * (O0 * Li) + x[rowoff + col];
        out[rowoff + col + 32] = gm * (O1 * Li) + x[rowoff + col + 32];
    }
}

// ---------------------------------------------------------------------------
extern "C" void kernel_launch(void* const* d_in, const int* in_sizes, int n_in,
                              void* d_out, int out_size, void* d_ws, size_t ws_size,
                              hipStream_t stream) {
    const float* x  = (const float*)d_in[0];
    const float* Wq = (const float*)d_in[1];
    const float* bq = (const float*)d_in[2];
    const float* Wk = (const float*)d_in[3];
    const float* bk = (const float*)d_in[4];
    const float* Wv = (const float*)d_in[5];
    const float* bv = (const float*)d_in[6];
    const float* gm = (const float*)d_in[7];
    float* out = (float*)d_out;

    // ws layout (bf16): Qb[4][4096][8] | Kb[4][4096][8] | Vt[4][64][4096]
    unsigned short* Qb = (unsigned short*)d_ws;
    unsigned short* Kb = Qb + 131072;
    unsigned short* Vt = Kb + 131072;   // total 2.62 MB

    hipLaunchKernelGGL(sagan_proj_kernel, dim3(256), dim3(512), 0, stream,
                       x, Wq, bq, Wk, bk, Wv, bv, Qb, Kb, Vt);
    hipLaunchKernelGGL(sagan_flash_kernel, dim3(1024), dim3(512), 0, stream,
                       Qb, Kb, Vt, x, gm, out);
}

// Round 3
// 50.001 us; speedup vs baseline: 1.9933x; 1.6322x over previous
//
#include <hip/hip_runtime.h>
#include <hip/hip_bf16.h>

// SAGAN self-attention, B=4 N=4096 C=64 d=8.
// Kernel 1: projections -> ws bf16: Qb[b][n][8] (pre-scaled log2e), Kb[b][n][8],
//           Vt[b][c][n] (pre-transposed = PV B-frag layout), 16B zero page.
// Kernel 2: flash attention, 512 blocks x 8 waves; wave w owns k-range
//           [w*512,w*512+512) for the block's 32 q-rows (2 q-tiles).
//           Permuted K-gather makes the S^T MFMA output land directly in the
//           PV A-fragment layout -> ZERO cross-lane shuffles in the hot loop.
//           Per-lane partial lsum; defer-max (T13, tau=8); LDS merge of the
//           8 k-split partials at the end.

typedef __attribute__((ext_vector_type(4))) float f32x4;
typedef __attribute__((ext_vector_type(8))) short short8;

#define LOG2E 1.44269504088896340736f

#if __has_builtin(__builtin_amdgcn_exp2f)
#define EXP2(x) __builtin_amdgcn_exp2f(x)
#else
#define EXP2(x) exp2f(x)
#endif

__device__ __forceinline__ unsigned short f2bf(float f) {
    __hip_bfloat16 h = __float2bfloat16(f);
    union { __hip_bfloat16 h; unsigned short u; } cv;
    cv.h = h;
    return cv.u;
}

__device__ __forceinline__ unsigned int pk2bf(float lo, float hi) {
    return (unsigned int)f2bf(lo) | ((unsigned int)f2bf(hi) << 16);
}

// ---------------------------------------------------------------------------
// Projection kernel: 256 blocks x 512 threads, 64 tokens per block.
// ---------------------------------------------------------------------------
__global__ __launch_bounds__(512) void sagan_proj_kernel(
    const float* __restrict__ x,
    const float* __restrict__ Wq, const float* __restrict__ bq,
    const float* __restrict__ Wk, const float* __restrict__ bk,
    const float* __restrict__ Wv, const float* __restrict__ bv,
    unsigned short* __restrict__ Qb, unsigned short* __restrict__ Kb,
    unsigned short* __restrict__ Vt, unsigned short* __restrict__ zp)
{
    __shared__ float xs[64][68];   // +4 pad: conflict-free strided reads
    const int tid = threadIdx.x;
    const int blk = blockIdx.x;          // 0..255
    const int tglob0 = blk << 6;         // first global token of this block
    const int b  = tglob0 >> 12;         // batch (N=4096 per batch)
    const int nb = tglob0 & 4095;        // n base within batch

    if (blk == 0 && tid < 8) zp[tid] = 0;   // 16B zero page for flash K pad

    // stage x tile [64 tokens][64 ch]: 8 floats per thread
    {
        const int t = tid >> 3, q8 = tid & 7;
        const float* src = x + (size_t)(tglob0 + t) * 64 + q8 * 8;
        *(f32x4*)&xs[t][q8 * 8]     = *(const f32x4*)(src);
        *(f32x4*)&xs[t][q8 * 8 + 4] = *(const f32x4*)(src + 4);
    }
    __syncthreads();

    // ---- V projection: thread = (channel c = tid&63, group tg = tid>>6) ----
    {
        const int c  = tid & 63;
        const int tg = tid >> 6;             // 0..7
        float wcol[64];
        #pragma unroll
        for (int cc = 0; cc < 64; ++cc) wcol[cc] = Wv[cc * 64 + c];
        const float bvc = bv[c];
        unsigned int wv[4];
        #pragma unroll
        for (int j = 0; j < 8; ++j) {
            const int tok = tg * 8 + j;       // wave-uniform -> LDS broadcast
            float acc = bvc;
            #pragma unroll
            for (int c4 = 0; c4 < 16; ++c4) {
                f32x4 xv = *(const f32x4*)&xs[tok][c4 * 4];
                acc += xv[0] * wcol[c4 * 4 + 0] + xv[1] * wcol[c4 * 4 + 1]
                     + xv[2] * wcol[c4 * 4 + 2] + xv[3] * wcol[c4 * 4 + 3];
            }
            if (j & 1) wv[j >> 1] |= ((unsigned int)f2bf(acc)) << 16;
            else       wv[j >> 1]  =  (unsigned int)f2bf(acc);
        }
        unsigned short* dst = Vt + ((size_t)(b * 64 + c) * 4096) + nb + tg * 8;
        *(uint4*)dst = make_uint4(wv[0], wv[1], wv[2], wv[3]);
    }

    // ---- Q/K projections: thread = (token = tid>>3, d = tid&7) ----
    {
        const int tok = tid >> 3;
        const int dd  = tid & 7;
        float q0 = bq[dd];
        float k0 = bk[dd];
        #pragma unroll
        for (int cc = 0; cc < 64; ++cc) {
            const float xv = xs[tok][cc];
            q0 += xv * Wq[cc * 8 + dd];
            k0 += xv * Wk[cc * 8 + dd];
        }
        const size_t toff = (size_t)(tglob0 + tok) * 8 + dd;
        Qb[toff] = f2bf(q0 * LOG2E);    // fold log2(e): softmax uses exp2
        Kb[toff] = f2bf(k0);
    }
}

// ---------------------------------------------------------------------------
// Flash attention: grid = B*N/32 = 512 blocks, 512 threads (8 waves).
// Wave w: k in [w*512, w*512+512) for 32 q-rows (2 MFMA q-tiles).
// Permuted K-gather: tile0 A-row r <- K[kt + (r>>2)*8 + (r&3)], tile1 +4.
// Then S^T output lane (g,ql) holds S[q=ql][k = kt+g*8+{0..7}] across the
// two tiles == the PV A-fragment element order. Zero shuffles.
// ---------------------------------------------------------------------------
__global__ __launch_bounds__(512, 4) void sagan_flash_kernel(
    const unsigned short* __restrict__ Qb, const unsigned short* __restrict__ Kb,
    const unsigned short* __restrict__ Vt, const unsigned short* __restrict__ zp,
    const float* __restrict__ x, const float* __restrict__ gamma_p,
    float* __restrict__ out)
{
    __shared__ float sacc[8][32][68];    // [wave][q-row][col](+4 pad) 69.6KB
    __shared__ float sml[8][2][32];      // [wave][m|l][q-row]          2KB

    const int tid  = threadIdx.x;
    const int lane = tid & 63;
    const int w    = tid >> 6;               // wave id = k-split index
    const int g    = lane >> 4;
    const int ql   = lane & 15;
    const int blk  = blockIdx.x;
    const int b    = blk >> 7;               // 128 blocks per batch
    const int qbase = (blk & 127) << 5;      // 32 q-rows per block

    const unsigned short* Kbase = Kb + (size_t)b * (4096 * 8);
    const unsigned short* Vbase = Vt + (size_t)b * (64 * 4096);

    const short8 zfrag = {0, 0, 0, 0, 0, 0, 0, 0};
    short8 qf0, qf1;                         // B-operand: Q[q=ql][d], g>0 pad
    {
        short8 a = *(const short8*)(Qb + (size_t)(b * 4096 + qbase + ql) * 8);
        short8 c = *(const short8*)(Qb + (size_t)(b * 4096 + qbase + 16 + ql) * 8);
        qf0 = (g == 0) ? a : zfrag;
        qf1 = (g == 0) ? c : zfrag;
    }

    const int kt0 = w << 9;                  // 512 k per wave

    // Permuted K pointers; g!=0 lanes read the zero page (stride 0).
    const unsigned short* kp0;
    const unsigned short* kp1;
    int kstep;
    if (g == 0) {
        const int kperm = ((ql >> 2) << 3) | (ql & 3);
        kp0 = Kbase + (size_t)(kt0 + kperm) * 8;
        kp1 = kp0 + 32;                      // +4 tokens
        kstep = 256;                         // 32 tokens * 8 shorts
    } else {
        kp0 = zp; kp1 = zp; kstep = 0;
    }

    // V B-operand rows: lane (g,ql) reads Vt[c=ct*16+ql][kt + g*8 .. +8)
    const unsigned short* vp0 = Vbase + (size_t)ql * 4096 + kt0 + g * 8;
    const unsigned short* vp1 = vp0 + 16 * 4096;
    const unsigned short* vp2 = vp0 + 32 * 4096;
    const unsigned short* vp3 = vp0 + 48 * 4096;

    f32x4 acc00 = {0.f,0.f,0.f,0.f}, acc01 = acc00, acc02 = acc00, acc03 = acc00;
    f32x4 acc10 = acc00, acc11 = acc00, acc12 = acc00, acc13 = acc00;
    float m0 = -1e30f, m1 = -1e30f, l0 = 0.f, l1 = 0.f;

    for (int it = 0; it < 16; ++it) {
        const short8 ka0 = *(const short8*)kp0;
        const short8 ka1 = *(const short8*)kp1;
        kp0 += kstep; kp1 += kstep;
        const short8 vf0 = *(const short8*)vp0; vp0 += 32;
        const short8 vf1 = *(const short8*)vp1; vp1 += 32;
        const short8 vf2 = *(const short8*)vp2; vp2 += 32;
        const short8 vf3 = *(const short8*)vp3; vp3 += 32;

        const f32x4 zc = {0.f, 0.f, 0.f, 0.f};

        // ================= q-tile 0 =================
        {
            f32x4 s0 = __builtin_amdgcn_mfma_f32_16x16x32_bf16(ka0, qf0, zc, 0, 0, 0);
            f32x4 s1 = __builtin_amdgcn_mfma_f32_16x16x32_bf16(ka1, qf0, zc, 0, 0, 0);
            // lane holds S[q=ql][k = kt + g*8 + {0..3}] (s0) and {4..7} (s1)
            float cm = fmaxf(fmaxf(fmaxf(s0[0], s0[1]), fmaxf(s0[2], s0[3])),
                             fmaxf(fmaxf(s1[0], s1[1]), fmaxf(s1[2], s1[3])));
            if (!__all(cm - m0 <= 8.f)) {
                float t = fmaxf(cm, __shfl_xor(cm, 16));
                t = fmaxf(t, __shfl_xor(t, 32));
                const float mn = fmaxf(m0, t);
                const float c = EXP2(m0 - mn);
                float cr[4];
                #pragma unroll
                for (int r = 0; r < 4; ++r) cr[r] = __shfl(c, (g << 2) | r);
                #pragma unroll
                for (int r = 0; r < 4; ++r) {
                    acc00[r] *= cr[r]; acc01[r] *= cr[r];
                    acc02[r] *= cr[r]; acc03[r] *= cr[r];
                }
                l0 *= c; m0 = mn;
            }
            float p[8];
            #pragma unroll
            for (int r = 0; r < 4; ++r) {
                p[r]     = EXP2(s0[r] - m0);
                p[4 + r] = EXP2(s1[r] - m0);
            }
            l0 += ((p[0] + p[1]) + (p[2] + p[3])) + ((p[4] + p[5]) + (p[6] + p[7]));
            union { unsigned int wd[4]; short8 v; } pa;
            pa.wd[0] = pk2bf(p[0], p[1]); pa.wd[1] = pk2bf(p[2], p[3]);
            pa.wd[2] = pk2bf(p[4], p[5]); pa.wd[3] = pk2bf(p[6], p[7]);
            acc00 = __builtin_amdgcn_mfma_f32_16x16x32_bf16(pa.v, vf0, acc00, 0, 0, 0);
            acc01 = __builtin_amdgcn_mfma_f32_16x16x32_bf16(pa.v, vf1, acc01, 0, 0, 0);
            acc02 = __builtin_amdgcn_mfma_f32_16x16x32_bf16(pa.v, vf2, acc02, 0, 0, 0);
            acc03 = __builtin_amdgcn_mfma_f32_16x16x32_bf16(pa.v, vf3, acc03, 0, 0, 0);
        }

        // ================= q-tile 1 =================
        {
            f32x4 s0 = __builtin_amdgcn_mfma_f32_16x16x32_bf16(ka0, qf1, zc, 0, 0, 0);
            f32x4 s1 = __builtin_amdgcn_mfma_f32_16x16x32_bf16(ka1, qf1, zc, 0, 0, 0);
            float cm = fmaxf(fmaxf(fmaxf(s0[0], s0[1]), fmaxf(s0[2], s0[3])),
                             fmaxf(fmaxf(s1[0], s1[1]), fmaxf(s1[2], s1[3])));
            if (!__all(cm - m1 <= 8.f)) {
                float t = fmaxf(cm, __shfl_xor(cm, 16));
                t = fmaxf(t, __shfl_xor(t, 32));
                const float mn = fmaxf(m1, t);
                const float c = EXP2(m1 - mn);
                float cr[4];
                #pragma unroll
                for (int r = 0; r < 4; ++r) cr[r] = __shfl(c, (g << 2) | r);
                #pragma unroll
                for (int r = 0; r < 4; ++r) {
                    acc10[r] *= cr[r]; acc11[r] *= cr[r];
                    acc12[r] *= cr[r]; acc13[r] *= cr[r];
                }
                l1 *= c; m1 = mn;
            }
            float p[8];
            #pragma unroll
            for (int r = 0; r < 4; ++r) {
                p[r]     = EXP2(s0[r] - m1);
                p[4 + r] = EXP2(s1[r] - m1);
            }
            l1 += ((p[0] + p[1]) + (p[2] + p[3])) + ((p[4] + p[5]) + (p[6] + p[7]));
            union { unsigned int wd[4]; short8 v; } pa;
            pa.wd[0] = pk2bf(p[0], p[1]); pa.wd[1] = pk2bf(p[2], p[3]);
            pa.wd[2] = pk2bf(p[4], p[5]); pa.wd[3] = pk2bf(p[6], p[7]);
            acc10 = __builtin_amdgcn_mfma_f32_16x16x32_bf16(pa.v, vf0, acc10, 0, 0, 0);
            acc11 = __builtin_amdgcn_mfma_f32_16x16x32_bf16(pa.v, vf1, acc11, 0, 0, 0);
            acc12 = __builtin_amdgcn_mfma_f32_16x16x32_bf16(pa.v, vf2, acc12, 0, 0, 0);
            acc13 = __builtin_amdgcn_mfma_f32_16x16x32_bf16(pa.v, vf3, acc13, 0, 0, 0);
        }
    }

    // ---- per-wave finalize: complete row-sums (once, not per chunk) ----
    l0 += __shfl_xor(l0, 16); l0 += __shfl_xor(l0, 32);
    l1 += __shfl_xor(l1, 16); l1 += __shfl_xor(l1, 32);

    #pragma unroll
    for (int r = 0; r < 4; ++r) {
        const int row = (g << 2) | r;
        float* d0 = &sacc[w][row][0];
        d0[ql] = acc00[r]; d0[16 + ql] = acc01[r];
        d0[32 + ql] = acc02[r]; d0[48 + ql] = acc03[r];
        float* d1 = &sacc[w][16 + row][0];
        d1[ql] = acc10[r]; d1[16 + ql] = acc11[r];
        d1[32 + ql] = acc12[r]; d1[48 + ql] = acc13[r];
    }
    if (g == 0) {
        sml[w][0][ql] = m0; sml[w][0][16 + ql] = m1;
        sml[w][1][ql] = l0; sml[w][1][16 + ql] = l1;
    }
    __syncthreads();

    // ---- merge 8 k-split partials: thread -> (row = tid>>4, 4 cols) ----
    {
        const int row = tid >> 4;            // 0..31
        const int cg  = tid & 15;
        float M = sml[0][0][row];
        #pragma unroll
        for (int ww = 1; ww < 8; ++ww) M = fmaxf(M, sml[ww][0][row]);
        float L = 0.f, O0 = 0.f, O1 = 0.f, O2 = 0.f, O3 = 0.f;
        #pragma unroll
        for (int ww = 0; ww < 8; ++ww) {
            const float sc = EXP2(sml[ww][0][row] - M);
            L += sml[ww][1][row] * sc;
            const float* s = &sacc[ww][row][0];
            O0 += s[cg] * sc;      O1 += s[16 + cg] * sc;
            O2 += s[32 + cg] * sc; O3 += s[48 + cg] * sc;
        }
        const float Li = 1.0f / L;
        const float gm = gamma_p[0];
        const size_t rowoff = ((size_t)(b * 4096 + qbase + row)) * 64;
        out[rowoff + cg]      = gm * (O0 * Li) + x[rowoff + cg];
        out[rowoff + 16 + cg] = gm * (O1 * Li) + x[rowoff + 16 + cg];
        out[rowoff + 32 + cg] = gm * (O2 * Li) + x[rowoff + 32 + cg];
        out[rowoff + 48 + cg] = gm * (O3 * Li) + x[rowoff + 48 + cg];
    }
}

// ---------------------------------------------------------------------------
extern "C" void kernel_launch(void* const* d_in, const int* in_sizes, int n_in,
                              void* d_out, int out_size, void* d_ws, size_t ws_size,
                              hipStream_t stream) {
    const float* x  = (const float*)d_in[0];
    const float* Wq = (const float*)d_in[1];
    const float* bq = (const float*)d_in[2];
    const float* Wk = (const float*)d_in[3];
    const float* bk = (const float*)d_in[4];
    const float* Wv = (const float*)d_in[5];
    const float* bv = (const float*)d_in[6];
    const float* gm = (const float*)d_in[7];
    float* out = (float*)d_out;

    // ws layout (bf16): Qb[4][4096][8] | Kb[4][4096][8] | Vt[4][64][4096] | zp[8]
    unsigned short* Qb = (unsigned short*)d_ws;
    unsigned short* Kb = Qb + 131072;
    unsigned short* Vt = Kb + 131072;
    unsigned short* zp = Vt + 1048576;   // 16B zero page (16B-aligned)

    hipLaunchKernelGGL(sagan_proj_kernel, dim3(256), dim3(512), 0, stream,
                       x, Wq, bq, Wk, bk, Wv, bv, Qb, Kb, Vt, zp);
    hipLaunchKernelGGL(sagan_flash_kernel, dim3(512), dim3(512), 0, stream,
                       Qb, Kb, Vt, zp, x, gm, out);
}